// Round 1
// baseline (3141.539 us; speedup 1.0000x reference)
//
#include <hip/hip_runtime.h>
#include <hip/hip_bf16.h>
#include <math.h>

static constexpr int Bn = 8, Cn = 32, Hn = 256, Wn = 256;
static constexpr size_t PLANE = (size_t)Hn * Wn;      // 65536

__device__ inline float ldconv(const float* p, size_t i) { return p[i]; }
__device__ inline float ldconv(const __hip_bfloat16* p, size_t i) { return __bfloat162float(p[i]); }

// ---------------------------------------------------------------------------
// IRNN vertical: up (dir 0) + down (dir 2). One thread per (b,c,w) column.
// Coalesced: consecutive threads -> consecutive w.
// ---------------------------------------------------------------------------
__global__ __launch_bounds__(256) void irnn_vert(const float* __restrict__ x,
        const float* __restrict__ w4, const float* __restrict__ b4,
        __hip_bfloat16* __restrict__ out)
{
    int bc = blockIdx.x;                 // b*Cn + c
    int b = bc >> 5, c = bc & 31;
    int wcol = threadIdx.x;
    float wd = w4[2 * Cn + c], bd = b4[2 * Cn + c];
    float wu = w4[0 * Cn + c], bu = b4[0 * Cn + c];
    const float* xp = x + (size_t)bc * PLANE + wcol;
    __hip_bfloat16* od = out + ((size_t)b * 4 * Cn + 2 * Cn + c) * PLANE + wcol;
    __hip_bfloat16* ou = out + ((size_t)b * 4 * Cn + 0 * Cn + c) * PLANE + wcol;

    // down: h[0] = x[0]; h[r] = relu(w*h[r-1] + b + x[r])
    float h = xp[0];
    od[0] = __float2bfloat16(h);
    for (int r = 1; r < Hn; ++r) {
        float xv = xp[(size_t)r * Wn];
        h = fmaxf(fmaf(wd, h, bd + xv), 0.f);
        od[(size_t)r * Wn] = __float2bfloat16(h);
    }
    // up: h[H-1] = x[H-1]; h[r] = relu(w*h[r+1] + b + x[r])
    h = xp[(size_t)(Hn - 1) * Wn];
    ou[(size_t)(Hn - 1) * Wn] = __float2bfloat16(h);
    for (int r = Hn - 2; r >= 0; --r) {
        float xv = xp[(size_t)r * Wn];
        h = fmaxf(fmaf(wu, h, bu + xv), 0.f);
        ou[(size_t)r * Wn] = __float2bfloat16(h);
    }
}

// ---------------------------------------------------------------------------
// IRNN horizontal: right (dir 1) + left (dir 3). One block per (b,c) plane,
// thread t owns row t. 64-column LDS chunks: coalesced load -> in-LDS scan
// (pitch 65 -> 2-way bank aliasing = free) -> coalesced store.
// ---------------------------------------------------------------------------
__global__ __launch_bounds__(256) void irnn_horiz(const float* __restrict__ x,
        const float* __restrict__ w4, const float* __restrict__ b4,
        __hip_bfloat16* __restrict__ out)
{
    __shared__ float tile[256 * 65];
    int bc = blockIdx.x;
    int b = bc >> 5, c = bc & 31;
    int tid = threadIdx.x;
    float wr = w4[1 * Cn + c], br = b4[1 * Cn + c];
    float wl = w4[3 * Cn + c], bl = b4[3 * Cn + c];
    const float* xp = x + (size_t)bc * PLANE;
    __hip_bfloat16* orr = out + ((size_t)b * 4 * Cn + 1 * Cn + c) * PLANE;
    __hip_bfloat16* ol  = out + ((size_t)b * 4 * Cn + 3 * Cn + c) * PLANE;

    float hv = 0.f;
    // ---- right: forward over column chunks ----
    for (int wc = 0; wc < 4; ++wc) {
        int w0 = wc << 6;
        __syncthreads();
        for (int i = tid; i < 256 * 64; i += 256) {
            int r = i >> 6, j = i & 63;
            tile[r * 65 + j] = xp[(size_t)r * Wn + w0 + j];
        }
        __syncthreads();
        #pragma unroll 1
        for (int j = 0; j < 64; ++j) {
            float xv = tile[tid * 65 + j];
            hv = (wc == 0 && j == 0) ? xv : fmaxf(fmaf(wr, hv, br + xv), 0.f);
            tile[tid * 65 + j] = hv;
        }
        __syncthreads();
        for (int i = tid; i < 256 * 64; i += 256) {
            int r = i >> 6, j = i & 63;
            orr[(size_t)r * Wn + w0 + j] = __float2bfloat16(tile[r * 65 + j]);
        }
    }
    // ---- left: backward over column chunks ----
    for (int wc = 3; wc >= 0; --wc) {
        int w0 = wc << 6;
        __syncthreads();
        for (int i = tid; i < 256 * 64; i += 256) {
            int r = i >> 6, j = i & 63;
            tile[r * 65 + j] = xp[(size_t)r * Wn + w0 + j];
        }
        __syncthreads();
        #pragma unroll 1
        for (int j = 63; j >= 0; --j) {
            float xv = tile[tid * 65 + j];
            hv = (wc == 3 && j == 63) ? xv : fmaxf(fmaf(wl, hv, bl + xv), 0.f);
            tile[tid * 65 + j] = hv;
        }
        __syncthreads();
        for (int i = tid; i < 256 * 64; i += 256) {
            int r = i >> 6, j = i & 63;
            ol[(size_t)r * Wn + w0 + j] = __float2bfloat16(tile[r * 65 + j]);
        }
    }
}

// ---------------------------------------------------------------------------
// Direct 3x3 SAME conv, Cout=32. Block: 256 threads -> 32x32 spatial tile,
// 8 output channels (blockIdx.y selects group of 8). Each thread: 2x2 pixels
// x 8 co register tile. Input staged in LDS in chunks of 8 input channels.
// ---------------------------------------------------------------------------
template <int CIN, typename TIN, bool RELU>
__global__ __launch_bounds__(256) void conv3x3(const TIN* __restrict__ in,
        const float* __restrict__ wgt, float* __restrict__ out)
{
    constexpr int CICH = 8;
    constexpr int PIT = 36;                    // even pitch -> aligned float2 reads
    __shared__ float sIn[CICH][34 * PIT];
    __shared__ float sW[CICH * 9 * 8];         // [cc][kh][kw][co]
    int tid = threadIdx.x;
    int tx = tid & 15, ty = tid >> 4;
    int tileX = (blockIdx.x & 7) << 5, tileY = (blockIdx.x >> 3) << 5;
    int cog = blockIdx.y, b = blockIdx.z;

    float acc[2][2][8];
    #pragma unroll
    for (int py = 0; py < 2; ++py)
        #pragma unroll
        for (int px = 0; px < 2; ++px)
            #pragma unroll
            for (int o = 0; o < 8; ++o) acc[py][px][o] = 0.f;

    for (int ci0 = 0; ci0 < CIN; ci0 += CICH) {
        __syncthreads();
        // stage 8 input channels of the 34x34 halo tile
        for (int i = tid; i < CICH * 34 * 34; i += 256) {
            int cc = i / (34 * 34);
            int rem = i - cc * (34 * 34);
            int yy = rem / 34, xx = rem - yy * 34;
            int gy = tileY + yy - 1, gx = tileX + xx - 1;
            float v = 0.f;
            if ((unsigned)gy < (unsigned)Hn && (unsigned)gx < (unsigned)Wn)
                v = ldconv(in, ((size_t)(b * CIN + ci0 + cc) * Hn + gy) * Wn + gx);
            sIn[cc][yy * PIT + xx] = v;
        }
        // stage weights: sW[(cc*9 + k)*8 + co]
        for (int i = tid; i < CICH * 9 * 8; i += 256) {
            int co = i & 7, rk = i >> 3;
            int cc = rk / 9, k = rk - cc * 9;
            sW[i] = wgt[((size_t)(cog * 8 + co) * CIN + ci0 + cc) * 9 + k];
        }
        __syncthreads();
        #pragma unroll
        for (int cc = 0; cc < CICH; ++cc) {
            float xv[4][4];
            #pragma unroll
            for (int r = 0; r < 4; ++r) {
                const float* rp = &sIn[cc][(ty * 2 + r) * PIT + tx * 2];
                float2 a  = *(const float2*)rp;
                float2 bb = *(const float2*)(rp + 2);
                xv[r][0] = a.x; xv[r][1] = a.y; xv[r][2] = bb.x; xv[r][3] = bb.y;
            }
            #pragma unroll
            for (int kh = 0; kh < 3; ++kh)
                #pragma unroll
                for (int kw = 0; kw < 3; ++kw) {
                    const float* wp = &sW[(cc * 9 + kh * 3 + kw) * 8];
                    float4 w0 = *(const float4*)wp;
                    float4 w1 = *(const float4*)(wp + 4);
                    #pragma unroll
                    for (int py = 0; py < 2; ++py)
                        #pragma unroll
                        for (int px = 0; px < 2; ++px) {
                            float v = xv[py + kh][px + kw];
                            acc[py][px][0] = fmaf(v, w0.x, acc[py][px][0]);
                            acc[py][px][1] = fmaf(v, w0.y, acc[py][px][1]);
                            acc[py][px][2] = fmaf(v, w0.z, acc[py][px][2]);
                            acc[py][px][3] = fmaf(v, w0.w, acc[py][px][3]);
                            acc[py][px][4] = fmaf(v, w1.x, acc[py][px][4]);
                            acc[py][px][5] = fmaf(v, w1.y, acc[py][px][5]);
                            acc[py][px][6] = fmaf(v, w1.z, acc[py][px][6]);
                            acc[py][px][7] = fmaf(v, w1.w, acc[py][px][7]);
                        }
                }
        }
    }
    #pragma unroll
    for (int o = 0; o < 8; ++o) {
        int co = cog * 8 + o;
        #pragma unroll
        for (int py = 0; py < 2; ++py) {
            int y = tileY + ty * 2 + py;
            #pragma unroll
            for (int px = 0; px < 2; ++px) {
                int xc = tileX + tx * 2 + px;
                float v = acc[py][px][o];
                if (RELU) v = fmaxf(v, 0.f);
                out[((size_t)(b * 32 + co) * Hn + y) * Wn + xc] = v;
            }
        }
    }
}

// ---------------------------------------------------------------------------
// 1x1 conv (32 -> 1) + sigmoid
// ---------------------------------------------------------------------------
__global__ __launch_bounds__(256) void conv1x1_sigmoid(const float* __restrict__ in,
        const float* __restrict__ w, float* __restrict__ out)
{
    int idx = blockIdx.x * 256 + threadIdx.x;    // b*H*W + pixel
    int b = idx >> 16;
    int pix = idx & 65535;
    const float* ip = in + (size_t)b * Cn * PLANE + pix;
    float s = 0.f;
    #pragma unroll
    for (int c = 0; c < Cn; ++c) s = fmaf(ip[(size_t)c * PLANE], w[c], s);
    out[idx] = 1.f / (1.f + expf(-s));
}

// ---------------------------------------------------------------------------
extern "C" void kernel_launch(void* const* d_in, const int* in_sizes, int n_in,
                              void* d_out, int out_size, void* d_ws, size_t ws_size,
                              hipStream_t stream)
{
    const float* x    = (const float*)d_in[0];
    const float* w_in = (const float*)d_in[1];
    const float* w2   = (const float*)d_in[2];
    const float* w3   = (const float*)d_in[3];
    const float* wo   = (const float*)d_in[4];
    const float* i1w  = (const float*)d_in[5];
    const float* i1b  = (const float*)d_in[6];
    const float* i2w  = (const float*)d_in[7];
    const float* i2b  = (const float*)d_in[8];
    float* out = (float*)d_out;

    char* ws = (char*)d_ws;
    float* bufA = (float*)ws;                                        // 8*32*256*256 f32 = 64 MiB (A -> B -> C)
    __hip_bfloat16* bufI = (__hip_bfloat16*)(ws + (size_t)Bn * Cn * PLANE * 4); // 8*128*256*256 bf16 = 128 MiB

    dim3 convGrid(64, 4, 8);   // 8x8 spatial tiles, 4 co-groups, 8 batches

    // A = conv_in(x)
    conv3x3<32, float, false><<<convGrid, 256, 0, stream>>>(x, w_in, bufA);
    // I1 = irnn(A)
    irnn_vert <<<Bn * Cn, 256, 0, stream>>>(bufA, i1w, i1b, bufI);
    irnn_horiz<<<Bn * Cn, 256, 0, stream>>>(bufA, i1w, i1b, bufI);
    // B = conv2(I1)  (overwrites A)
    conv3x3<128, __hip_bfloat16, false><<<convGrid, 256, 0, stream>>>(bufI, w2, bufA);
    // I2 = irnn(B)   (overwrites I1)
    irnn_vert <<<Bn * Cn, 256, 0, stream>>>(bufA, i2w, i2b, bufI);
    irnn_horiz<<<Bn * Cn, 256, 0, stream>>>(bufA, i2w, i2b, bufI);
    // C = relu(conv3(I2))  (overwrites B)
    conv3x3<128, __hip_bfloat16, true><<<convGrid, 256, 0, stream>>>(bufI, w3, bufA);
    // mask = sigmoid(conv_out(C))
    conv1x1_sigmoid<<<(Bn * Hn * Wn) / 256, 256, 0, stream>>>(bufA, wo, out);
}

// Round 2
// 800.750 us; speedup vs baseline: 3.9232x; 3.9232x over previous
//
#include <hip/hip_runtime.h>
#include <hip/hip_bf16.h>
#include <math.h>

static constexpr int Bn = 8, Cn = 32, Hn = 256, Wn = 256;
static constexpr size_t PLANE = (size_t)Hn * Wn;   // 65536

typedef __attribute__((ext_vector_type(8))) short bf16x8;   // 8 bf16 = 4 VGPRs (MFMA A/B frag)
typedef __attribute__((ext_vector_type(4))) float f32x4;    // MFMA C/D frag
typedef __attribute__((ext_vector_type(4))) short s16x4;    // 4 bf16 store

__device__ inline short bf16bits(float v) {
    __hip_bfloat16 h = __float2bfloat16(v);
    union { __hip_bfloat16 h; short s; } u; u.h = h;
    return u.s;
}

// ---------------------------------------------------------------------------
// Pack conv weights fp32 OIHW [32][CIN][3][3] -> bf16 wp[s=kh*3+kw][cb][g][n][j]
// exactly in MFMA B-fragment lane order (n = co in tile, k = g*8+j = ci in blk).
// ---------------------------------------------------------------------------
template <int CIN>
__global__ __launch_bounds__(256) void pack_w(const float* __restrict__ w,
                                              __hip_bfloat16* __restrict__ wp)
{
    constexpr int CB = CIN / 32;
    int idx = blockIdx.x * 256 + threadIdx.x;        // 9*CB*1024 total
    int j = idx & 7, n = (idx >> 3) & 31, g = (idx >> 8) & 3;
    int rest = idx >> 10;                            // s*CB + cb
    int cb = rest % CB, s = rest / CB;
    int ci = cb * 32 + g * 8 + j;
    float v = w[((size_t)(n * CIN + ci) * 3 + s / 3) * 3 + (s % 3)];
    wp[idx] = __float2bfloat16(v);
}

// ---------------------------------------------------------------------------
// x (fp32 NCHW, C=32) -> bf16 NHWC [b][y][x][32]. LDS transpose, 32-px chunks.
// ---------------------------------------------------------------------------
__global__ __launch_bounds__(256) void x_to_nhwc(const float* __restrict__ in,
                                                 __hip_bfloat16* __restrict__ out)
{
    __shared__ unsigned int shU[32 * 17];            // ushort view pitch 34
    unsigned short* sh16 = (unsigned short*)shU;
    int tid = threadIdx.x;
    int px0 = blockIdx.x * 32;
    int b = blockIdx.y;
    const float2* in2 = (const float2*)(in + ((size_t)b * 32) * PLANE + px0);
    for (int i = tid; i < 512; i += 256) {           // 32 ch x 16 px-pairs
        int ch = i >> 4, pxp = i & 15;
        float2 v = in2[(size_t)ch * (PLANE / 2) + pxp];
        unsigned int lo = (unsigned short)bf16bits(v.x);
        unsigned int hi = (unsigned short)bf16bits(v.y);
        shU[ch * 17 + pxp] = lo | (hi << 16);
    }
    __syncthreads();
    unsigned int* out32 = (unsigned int*)(out + ((size_t)b * PLANE + px0) * 32);
    for (int i = tid; i < 512; i += 256) {           // 32 px x 16 ch-pairs
        int px = i >> 4, chp = i & 15;
        unsigned int v = (unsigned int)sh16[(2 * chp) * 34 + px]
                       | ((unsigned int)sh16[(2 * chp + 1) * 34 + px] << 16);
        out32[(size_t)px * 16 + chp] = v;
    }
}

// ---------------------------------------------------------------------------
// MFMA implicit-GEMM 3x3 SAME conv. Input NHWC bf16 (CIN ch contiguous),
// weights pre-packed B-frag order, output NCHW bf16 (32 co).
// Block = 4 waves; wave w: row y = by*4+w, 32 consecutive x (2 m-tiles),
// all 32 co (2 n-tiles). K-loop = 9 shifts x CB ci-blocks of 32.
// A-frags straight from global (L2/L3 absorbs the 9x shift re-reads); no LDS.
// ---------------------------------------------------------------------------
template <int CIN, bool RELU>
__global__ __launch_bounds__(256) void conv_mfma(const __hip_bfloat16* __restrict__ in,
        const __hip_bfloat16* __restrict__ wp, __hip_bfloat16* __restrict__ out)
{
    constexpr int CB = CIN / 32;
    int tid = threadIdx.x;
    int lane = tid & 63, wave = tid >> 6;
    int m = lane & 15, g = lane >> 4;                // A: row m, k-group g
    int x0 = blockIdx.x * 32;
    int y  = blockIdx.y * 4 + wave;
    int b  = blockIdx.z;

    f32x4 acc[2][2] = {};
    const short* inS = (const short*)in;
    const short* wpS = (const short*)wp;
    const bf16x8 zf = {};

    #pragma unroll
    for (int s = 0; s < 9; ++s) {
        int dy = s / 3 - 1, dx = s % 3 - 1;
        int yy = y + dy;
        if ((unsigned)yy >= (unsigned)Hn) continue;  // wave-uniform: SAME zero pad
        int xx0 = x0 + m + dx;
        int xx1 = xx0 + 16;
        bool ok0 = (unsigned)xx0 < (unsigned)Wn;
        bool ok1 = (unsigned)xx1 < (unsigned)Wn;
        const short* arow = inS + ((size_t)b * Hn + yy) * Wn * CIN;
        #pragma unroll
        for (int cb = 0; cb < CB; ++cb) {
            int ci = cb * 32 + g * 8;
            bf16x8 a0 = zf, a1 = zf;
            if (ok0) a0 = *(const bf16x8*)(arow + (size_t)xx0 * CIN + ci);
            if (ok1) a1 = *(const bf16x8*)(arow + (size_t)xx1 * CIN + ci);
            const short* wb = wpS + (size_t)(((s * CB + cb) * 4 + g) * 32) * 8;
            bf16x8 b0 = *(const bf16x8*)(wb + m * 8);
            bf16x8 b1 = *(const bf16x8*)(wb + (16 + m) * 8);
            acc[0][0] = __builtin_amdgcn_mfma_f32_16x16x32_bf16(a0, b0, acc[0][0], 0, 0, 0);
            acc[0][1] = __builtin_amdgcn_mfma_f32_16x16x32_bf16(a0, b1, acc[0][1], 0, 0, 0);
            acc[1][0] = __builtin_amdgcn_mfma_f32_16x16x32_bf16(a1, b0, acc[1][0], 0, 0, 0);
            acc[1][1] = __builtin_amdgcn_mfma_f32_16x16x32_bf16(a1, b1, acc[1][1], 0, 0, 0);
        }
    }
    // C/D layout: col = lane&15 -> co within n-tile; row = g*4 + reg -> x offset.
    short* outS = (short*)out;
    #pragma unroll
    for (int mt = 0; mt < 2; ++mt) {
        int xb = x0 + mt * 16 + g * 4;
        #pragma unroll
        for (int nt = 0; nt < 2; ++nt) {
            int co = nt * 16 + m;
            s16x4 ov;
            #pragma unroll
            for (int r = 0; r < 4; ++r) {
                float v = acc[mt][nt][r];
                if (RELU) v = fmaxf(v, 0.f);
                ov[r] = bf16bits(v);
            }
            *(s16x4*)(outS + (((size_t)(b * 32 + co) * Hn + y) * Wn + xb)) = ov;
        }
    }
}

// ---------------------------------------------------------------------------
// IRNN vertical (up=dir0 reverse / down=dir2 fwd). Input NCHW bf16 conv-out,
// output NHWC bf16 [b][y][x][128] at channel dir*32+c (c-major lanes ->
// coalesced 64B NHWC writes). Thread = (xo, c); per-y gathers hit L1.
// ---------------------------------------------------------------------------
__global__ __launch_bounds__(256) void irnn_vert(const __hip_bfloat16* __restrict__ A,
        const float* __restrict__ w4, const float* __restrict__ b4,
        __hip_bfloat16* __restrict__ I)
{
    int tid = threadIdx.x;
    int c = tid & 31, xo = tid >> 5;
    int x = blockIdx.x * 8 + xo;
    int dir = blockIdx.y ? 2 : 0;
    int b = blockIdx.z;
    float w = w4[dir * 32 + c], bb = b4[dir * 32 + c];
    const __hip_bfloat16* a = A + ((size_t)(b * 32 + c)) * PLANE + x;
    __hip_bfloat16* o = I + ((size_t)b * PLANE + x) * 128 + dir * 32 + c;

    if (dir == 2) {                                   // down: y = 0 .. 255
        float h = __bfloat162float(a[0]);
        o[0] = __float2bfloat16(h);
        for (int yv = 1; yv < Hn; ++yv) {
            float xv = __bfloat162float(a[(size_t)yv * Wn]);
            h = fmaxf(fmaf(w, h, bb + xv), 0.f);
            o[(size_t)yv * Wn * 128] = __float2bfloat16(h);
        }
    } else {                                          // up: y = 255 .. 0
        float h = __bfloat162float(a[(size_t)(Hn - 1) * Wn]);
        o[(size_t)(Hn - 1) * Wn * 128] = __float2bfloat16(h);
        for (int yv = Hn - 2; yv >= 0; --yv) {
            float xv = __bfloat162float(a[(size_t)yv * Wn]);
            h = fmaxf(fmaf(w, h, bb + xv), 0.f);
            o[(size_t)yv * Wn * 128] = __float2bfloat16(h);
        }
    }
}

// ---------------------------------------------------------------------------
// IRNN horizontal (right=dir1 fwd / left=dir3 reverse). Thread = (yo, c);
// sequential along x, per-plane rows stay hot in L1.
// ---------------------------------------------------------------------------
__global__ __launch_bounds__(256) void irnn_horiz(const __hip_bfloat16* __restrict__ A,
        const float* __restrict__ w4, const float* __restrict__ b4,
        __hip_bfloat16* __restrict__ I)
{
    int tid = threadIdx.x;
    int c = tid & 31, yo = tid >> 5;
    int y = blockIdx.x * 8 + yo;
    int dir = blockIdx.y ? 3 : 1;
    int b = blockIdx.z;
    float w = w4[dir * 32 + c], bb = b4[dir * 32 + c];
    const __hip_bfloat16* a = A + ((size_t)(b * 32 + c)) * PLANE + (size_t)y * Wn;
    __hip_bfloat16* o = I + ((size_t)b * PLANE + (size_t)y * Wn) * 128 + dir * 32 + c;

    if (dir == 1) {                                   // right: x = 0 .. 255
        float h = __bfloat162float(a[0]);
        o[0] = __float2bfloat16(h);
        for (int xv_i = 1; xv_i < Wn; ++xv_i) {
            float xv = __bfloat162float(a[xv_i]);
            h = fmaxf(fmaf(w, h, bb + xv), 0.f);
            o[(size_t)xv_i * 128] = __float2bfloat16(h);
        }
    } else {                                          // left: x = 255 .. 0
        float h = __bfloat162float(a[Wn - 1]);
        o[(size_t)(Wn - 1) * 128] = __float2bfloat16(h);
        for (int xv_i = Wn - 2; xv_i >= 0; --xv_i) {
            float xv = __bfloat162float(a[xv_i]);
            h = fmaxf(fmaf(w, h, bb + xv), 0.f);
            o[(size_t)xv_i * 128] = __float2bfloat16(h);
        }
    }
}

// ---------------------------------------------------------------------------
// 1x1 conv (32 -> 1) + sigmoid, bf16 NCHW input.
// ---------------------------------------------------------------------------
__global__ __launch_bounds__(256) void conv1x1_sigmoid(const __hip_bfloat16* __restrict__ in,
        const float* __restrict__ w, float* __restrict__ out)
{
    int idx = blockIdx.x * 256 + threadIdx.x;
    int b = idx >> 16, pix = idx & 65535;
    const __hip_bfloat16* ip = in + (size_t)b * 32 * PLANE + pix;
    float s = 0.f;
    #pragma unroll
    for (int c = 0; c < 32; ++c)
        s = fmaf(__bfloat162float(ip[(size_t)c * PLANE]), w[c], s);
    out[idx] = 1.f / (1.f + expf(-s));
}

// ---------------------------------------------------------------------------
extern "C" void kernel_launch(void* const* d_in, const int* in_sizes, int n_in,
                              void* d_out, int out_size, void* d_ws, size_t ws_size,
                              hipStream_t stream)
{
    const float* x    = (const float*)d_in[0];
    const float* w_in = (const float*)d_in[1];
    const float* w2   = (const float*)d_in[2];
    const float* w3   = (const float*)d_in[3];
    const float* wo   = (const float*)d_in[4];
    const float* i1w  = (const float*)d_in[5];
    const float* i1b  = (const float*)d_in[6];
    const float* i2w  = (const float*)d_in[7];
    const float* i2b  = (const float*)d_in[8];
    float* out = (float*)d_out;

    char* ws = (char*)d_ws;
    // I region (128 MiB): NHWC bf16 [8][256][256][128]; xT (32 MiB) aliases its head
    __hip_bfloat16* I  = (__hip_bfloat16*)ws;
    __hip_bfloat16* xT = (__hip_bfloat16*)ws;
    // A region (32 MiB @ 128 MiB): conv out NCHW bf16 [8][32][256][256]
    __hip_bfloat16* A  = (__hip_bfloat16*)(ws + ((size_t)128 << 20));
    // packed weights @ 160 MiB
    __hip_bfloat16* wp1 = (__hip_bfloat16*)(ws + ((size_t)160 << 20));
    __hip_bfloat16* wp2 = (__hip_bfloat16*)(ws + ((size_t)160 << 20) + (32 << 10));
    __hip_bfloat16* wp3 = (__hip_bfloat16*)(ws + ((size_t)160 << 20) + (112 << 10));

    dim3 convGrid(8, 64, 8);      // 8 x-chunks(32), 64 y-chunks(4 rows/wave), 8 b
    dim3 irnnGrid(32, 2, 8);      // 32 line-chunks(8), 2 dirs, 8 b

    pack_w<32> <<<36,  256, 0, stream>>>(w_in, wp1);
    pack_w<128><<<144, 256, 0, stream>>>(w2, wp2);
    pack_w<128><<<144, 256, 0, stream>>>(w3, wp3);

    x_to_nhwc<<<dim3(2048, 8), 256, 0, stream>>>(x, xT);
    conv_mfma<32, false><<<convGrid, 256, 0, stream>>>(xT, wp1, A);

    irnn_vert <<<irnnGrid, 256, 0, stream>>>(A, i1w, i1b, I);
    irnn_horiz<<<irnnGrid, 256, 0, stream>>>(A, i1w, i1b, I);
    conv_mfma<128, false><<<convGrid, 256, 0, stream>>>(I, wp2, A);

    irnn_vert <<<irnnGrid, 256, 0, stream>>>(A, i2w, i2b, I);
    irnn_horiz<<<irnnGrid, 256, 0, stream>>>(A, i2w, i2b, I);
    conv_mfma<128, true><<<convGrid, 256, 0, stream>>>(I, wp3, A);

    conv1x1_sigmoid<<<2048, 256, 0, stream>>>(A, wo, out);
}

// Round 3
// 455.535 us; speedup vs baseline: 6.8964x; 1.7578x over previous
//
#include <hip/hip_runtime.h>
#include <hip/hip_bf16.h>
#include <math.h>

static constexpr int Bn = 8, Cn = 32, Hn = 256, Wn = 256;
static constexpr size_t PLANE = (size_t)Hn * Wn;   // 65536

typedef __attribute__((ext_vector_type(8))) short bf16x8;   // MFMA A/B frag (4 VGPRs)
typedef __attribute__((ext_vector_type(4))) float f32x4;    // MFMA C/D frag
typedef __attribute__((ext_vector_type(4))) short s16x4;    // 4 bf16 = 8 B store
typedef __attribute__((ext_vector_type(4))) int   i32x4;    // 16 B copy

__device__ inline short bf16bits(float v) {
    union { __hip_bfloat16 h; short s; } u; u.h = __float2bfloat16(v);
    return u.s;
}
__device__ inline float bits2f(short s) {
    union { unsigned int u; float f; } u; u.u = ((unsigned int)(unsigned short)s) << 16;
    return u.f;
}

// ---------------------------------------------------------------------------
// Pack conv weights fp32 OIHW [32][CIN][3][3] -> bf16 wp[cb][s][mt][m][g][j]
// = MFMA A-fragment order (M-side = co): lane(m,g) reads W[co=mt*16+m][k=g*8+j].
// ---------------------------------------------------------------------------
template <int CIN>
__global__ __launch_bounds__(256) void pack_w(const float* __restrict__ w,
                                              __hip_bfloat16* __restrict__ wp)
{
    int idx = blockIdx.x * 256 + threadIdx.x;        // total 9*CB*1024
    int j = idx & 7, g = (idx >> 3) & 3, m = (idx >> 5) & 15, mt = (idx >> 9) & 1;
    int rest = idx >> 10;
    int s = rest % 9, cb = rest / 9;
    int co = mt * 16 + m;
    int ci = cb * 32 + g * 8 + j;
    float v = w[((size_t)(co * CIN + ci) * 3 + s / 3) * 3 + (s % 3)];
    wp[idx] = __float2bfloat16(v);
}

// ---------------------------------------------------------------------------
// x (fp32 NCHW, C=32) -> bf16 NHWC [b][y][x][32]. LDS transpose, 32-px chunks.
// ---------------------------------------------------------------------------
__global__ __launch_bounds__(256) void x_to_nhwc(const float* __restrict__ in,
                                                 __hip_bfloat16* __restrict__ out)
{
    __shared__ unsigned int shU[32 * 17];
    unsigned short* sh16 = (unsigned short*)shU;
    int tid = threadIdx.x;
    int px0 = blockIdx.x * 32;
    int b = blockIdx.y;
    const float2* in2 = (const float2*)(in + ((size_t)b * 32) * PLANE + px0);
    for (int i = tid; i < 512; i += 256) {
        int ch = i >> 4, pxp = i & 15;
        float2 v = in2[(size_t)ch * (PLANE / 2) + pxp];
        unsigned int lo = (unsigned short)bf16bits(v.x);
        unsigned int hi = (unsigned short)bf16bits(v.y);
        shU[ch * 17 + pxp] = lo | (hi << 16);
    }
    __syncthreads();
    unsigned int* out32 = (unsigned int*)(out + ((size_t)b * PLANE + px0) * 32);
    for (int i = tid; i < 512; i += 256) {
        int px = i >> 4, chp = i & 15;
        unsigned int v = (unsigned int)sh16[(2 * chp) * 34 + px]
                       | ((unsigned int)sh16[(2 * chp + 1) * 34 + px] << 16);
        out32[(size_t)px * 16 + chp] = v;
    }
}

// ---------------------------------------------------------------------------
// MFMA implicit-GEMM 3x3 SAME conv, NHWC bf16 in -> NHWC bf16 out (32 co).
// GEMM roles: M = co (weights = A operand), N = x (pixels = B operand).
// Block (4 waves) tile: 16 y x 32 x x 32 co; wave = 4 y-rows.
// LDS: input slab [18 y][34 x][32 ci] (zero-padded halo -> branch-free K-loop)
//      + per-cb weight slice [9 s][2 mt][16 m][4 g][8 j]. cb-loop stages both.
// ---------------------------------------------------------------------------
template <int CIN, bool RELU>
__global__ __launch_bounds__(256, 2) void conv_mfma(const __hip_bfloat16* __restrict__ in,
        const __hip_bfloat16* __restrict__ wp, __hip_bfloat16* __restrict__ out)
{
    constexpr int CB = CIN / 32;
    __shared__ short sIn[18 * 34 * 32];      // 38.25 KiB
    __shared__ short sW[9 * 1024];           // 18 KiB
    int tid = threadIdx.x;
    int lane = tid & 63, wave = tid >> 6;
    int m = lane & 15, g = lane >> 4;
    int x0 = blockIdx.x * 32, y0 = blockIdx.y * 16, b = blockIdx.z;

    f32x4 acc[4][2][2] = {};                 // [wy][mt(co)][nt(x)]
    const short* inS = (const short*)in;
    const short* wpS = (const short*)wp;

    for (int cb = 0; cb < CB; ++cb) {
        __syncthreads();
        // stage input slab: rows y0-1..y0+16, cols x0-1..x0+32, 32 ci of block cb
        for (int i = tid; i < 2448; i += 256) {          // 18*34*4 x 16B
            int ci16 = i & 3;
            int q = i >> 2;
            int xx = q % 34, yy = q / 34;
            int gy = y0 + yy - 1, gx = x0 + xx - 1;
            i32x4 v = {};
            if ((unsigned)gy < (unsigned)Hn && (unsigned)gx < (unsigned)Wn)
                v = *(const i32x4*)(inS + ((size_t)((b * 256 + gy) * 256 + gx)) * CIN
                                        + cb * 32 + ci16 * 8);
            *(i32x4*)(sIn + (yy * 34 + xx) * 32 + ci16 * 8) = v;
        }
        // stage weight slice for cb (straight 18 KiB copy)
        for (int i = tid; i < 1152; i += 256)
            *(i32x4*)(sW + i * 8) = *(const i32x4*)(wpS + (size_t)cb * 9216 + i * 8);
        __syncthreads();

        #pragma unroll
        for (int s = 0; s < 9; ++s) {
            int dy = s / 3 - 1, dx = s % 3 - 1;
            bf16x8 wf0 = *(const bf16x8*)(sW + ((s * 2 + 0) * 16 + m) * 32 + g * 8);
            bf16x8 wf1 = *(const bf16x8*)(sW + ((s * 2 + 1) * 16 + m) * 32 + g * 8);
            #pragma unroll
            for (int wy = 0; wy < 4; ++wy) {
                int yy = wave * 4 + wy + dy + 1;          // 0..17, always in-slab
                const short* rp = sIn + (yy * 34 + m + dx + 1) * 32 + g * 8;
                bf16x8 b0 = *(const bf16x8*)rp;
                bf16x8 b1 = *(const bf16x8*)(rp + 16 * 32);
                acc[wy][0][0] = __builtin_amdgcn_mfma_f32_16x16x32_bf16(wf0, b0, acc[wy][0][0], 0, 0, 0);
                acc[wy][1][0] = __builtin_amdgcn_mfma_f32_16x16x32_bf16(wf1, b0, acc[wy][1][0], 0, 0, 0);
                acc[wy][0][1] = __builtin_amdgcn_mfma_f32_16x16x32_bf16(wf0, b1, acc[wy][0][1], 0, 0, 0);
                acc[wy][1][1] = __builtin_amdgcn_mfma_f32_16x16x32_bf16(wf1, b1, acc[wy][1][1], 0, 0, 0);
            }
        }
    }

    // D layout: row (= co-in-tile) = g*4 + reg, col (= x-offset) = lane&15.
    short* outS = (short*)out;
    #pragma unroll
    for (int wy = 0; wy < 4; ++wy) {
        int y = y0 + wave * 4 + wy;
        #pragma unroll
        for (int nt = 0; nt < 2; ++nt) {
            int x = x0 + nt * 16 + m;
            size_t base = ((size_t)((b * 256 + y) * 256 + x)) * 32;
            #pragma unroll
            for (int mt = 0; mt < 2; ++mt) {
                int co = mt * 16 + g * 4;
                s16x4 ov;
                #pragma unroll
                for (int r = 0; r < 4; ++r) {
                    float v = acc[wy][mt][nt][r];
                    if (RELU) v = fmaxf(v, 0.f);
                    ov[r] = bf16bits(v);
                }
                *(s16x4*)(outS + base + co) = ov;
            }
        }
    }
}

// ---------------------------------------------------------------------------
// IRNN vertical (up=0 / down=2). A is NHWC bf16 C=32; I is NHWC bf16 C=128.
// Thread (c=tid&31, xo=tid>>5): lanes c-fast -> reads 128 B dense, writes
// 64 B segments. Fully coalesced, no LDS.
// ---------------------------------------------------------------------------
__global__ __launch_bounds__(256) void irnn_vert(const __hip_bfloat16* __restrict__ A,
        const float* __restrict__ w4, const float* __restrict__ b4,
        __hip_bfloat16* __restrict__ I)
{
    int tid = threadIdx.x;
    int c = tid & 31, xo = tid >> 5;
    int x = blockIdx.x * 8 + xo;
    int dir = blockIdx.y ? 2 : 0;
    int b = blockIdx.z;
    float w = w4[dir * 32 + c], bb = b4[dir * 32 + c];
    const short* a = (const short*)A + ((size_t)b * PLANE + x) * 32 + c;
    short* o = (short*)I + ((size_t)b * PLANE + x) * 128 + dir * 32 + c;
    const size_t as = (size_t)Wn * 32, os = (size_t)Wn * 128;

    if (dir == 2) {
        float h = bits2f(a[0]);
        o[0] = bf16bits(h);
        #pragma unroll 4
        for (int y = 1; y < Hn; ++y) {
            float xv = bits2f(a[(size_t)y * as]);
            h = fmaxf(fmaf(w, h, bb + xv), 0.f);
            o[(size_t)y * os] = bf16bits(h);
        }
    } else {
        float h = bits2f(a[(size_t)(Hn - 1) * as]);
        o[(size_t)(Hn - 1) * os] = bf16bits(h);
        #pragma unroll 4
        for (int y = Hn - 2; y >= 0; --y) {
            float xv = bits2f(a[(size_t)y * as]);
            h = fmaxf(fmaf(w, h, bb + xv), 0.f);
            o[(size_t)y * os] = bf16bits(h);
        }
    }
}

// ---------------------------------------------------------------------------
// IRNN horizontal (right=1 / left=3). Thread (c, yo): lanes c-fast.
// ---------------------------------------------------------------------------
__global__ __launch_bounds__(256) void irnn_horiz(const __hip_bfloat16* __restrict__ A,
        const float* __restrict__ w4, const float* __restrict__ b4,
        __hip_bfloat16* __restrict__ I)
{
    int tid = threadIdx.x;
    int c = tid & 31, yo = tid >> 5;
    int y = blockIdx.x * 8 + yo;
    int dir = blockIdx.y ? 3 : 1;
    int b = blockIdx.z;
    float w = w4[dir * 32 + c], bb = b4[dir * 32 + c];
    const short* a = (const short*)A + ((size_t)b * PLANE + (size_t)y * Wn) * 32 + c;
    short* o = (short*)I + ((size_t)b * PLANE + (size_t)y * Wn) * 128 + dir * 32 + c;

    if (dir == 1) {
        float h = bits2f(a[0]);
        o[0] = bf16bits(h);
        #pragma unroll 4
        for (int x = 1; x < Wn; ++x) {
            float xv = bits2f(a[(size_t)x * 32]);
            h = fmaxf(fmaf(w, h, bb + xv), 0.f);
            o[(size_t)x * 128] = bf16bits(h);
        }
    } else {
        float h = bits2f(a[(size_t)(Wn - 1) * 32]);
        o[(size_t)(Wn - 1) * 128] = bf16bits(h);
        #pragma unroll 4
        for (int x = Wn - 2; x >= 0; --x) {
            float xv = bits2f(a[(size_t)x * 32]);
            h = fmaxf(fmaf(w, h, bb + xv), 0.f);
            o[(size_t)x * 128] = bf16bits(h);
        }
    }
}

// ---------------------------------------------------------------------------
// 1x1 conv (32 -> 1) + sigmoid, NHWC bf16 input. Thread per pixel: 64 B
// contiguous per lane via 4x b128 loads.
// ---------------------------------------------------------------------------
__global__ __launch_bounds__(256) void conv1x1_sigmoid(const __hip_bfloat16* __restrict__ in,
        const float* __restrict__ w, float* __restrict__ out)
{
    int idx = blockIdx.x * 256 + threadIdx.x;    // global pixel (b*H*W + pix)
    const short* ip = (const short*)in + (size_t)idx * 32;
    float s = 0.f;
    #pragma unroll
    for (int k = 0; k < 4; ++k) {
        bf16x8 v = *(const bf16x8*)(ip + k * 8);
        #pragma unroll
        for (int j = 0; j < 8; ++j)
            s = fmaf(bits2f(v[j]), w[k * 8 + j], s);
    }
    out[idx] = 1.f / (1.f + expf(-s));
}

// ---------------------------------------------------------------------------
extern "C" void kernel_launch(void* const* d_in, const int* in_sizes, int n_in,
                              void* d_out, int out_size, void* d_ws, size_t ws_size,
                              hipStream_t stream)
{
    const float* x    = (const float*)d_in[0];
    const float* w_in = (const float*)d_in[1];
    const float* w2   = (const float*)d_in[2];
    const float* w3   = (const float*)d_in[3];
    const float* wo   = (const float*)d_in[4];
    const float* i1w  = (const float*)d_in[5];
    const float* i1b  = (const float*)d_in[6];
    const float* i2w  = (const float*)d_in[7];
    const float* i2b  = (const float*)d_in[8];
    float* out = (float*)d_out;

    char* ws = (char*)d_ws;
    // I: NHWC bf16 [8][256][256][128] = 128 MiB @ 0 (xT NHWC C=32 aliases head)
    __hip_bfloat16* I  = (__hip_bfloat16*)ws;
    __hip_bfloat16* xT = (__hip_bfloat16*)ws;
    // A: NHWC bf16 [8][256][256][32] = 32 MiB @ 128 MiB
    __hip_bfloat16* A  = (__hip_bfloat16*)(ws + ((size_t)128 << 20));
    // packed weights @ 160 MiB (ws >= 192 MiB proven in round 1)
    __hip_bfloat16* wp1 = (__hip_bfloat16*)(ws + ((size_t)160 << 20));
    __hip_bfloat16* wp2 = (__hip_bfloat16*)(ws + ((size_t)160 << 20) + ((size_t)1 << 19));
    __hip_bfloat16* wp3 = (__hip_bfloat16*)(ws + ((size_t)160 << 20) + ((size_t)2 << 19));

    dim3 convGrid(8, 16, 8);      // 32-x strips, 16-y chunks, 8 b
    dim3 irnnGrid(32, 2, 8);      // 8-line chunks, 2 dirs, 8 b

    pack_w<32> <<<36,  256, 0, stream>>>(w_in, wp1);
    pack_w<128><<<144, 256, 0, stream>>>(w2, wp2);
    pack_w<128><<<144, 256, 0, stream>>>(w3, wp3);

    x_to_nhwc<<<dim3(2048, 8), 256, 0, stream>>>(x, xT);
    conv_mfma<32, false><<<convGrid, 256, 0, stream>>>(xT, wp1, A);

    irnn_vert <<<irnnGrid, 256, 0, stream>>>(A, i1w, i1b, I);
    irnn_horiz<<<irnnGrid, 256, 0, stream>>>(A, i1w, i1b, I);
    conv_mfma<128, false><<<convGrid, 256, 0, stream>>>(I, wp2, A);

    irnn_vert <<<irnnGrid, 256, 0, stream>>>(A, i2w, i2b, I);
    irnn_horiz<<<irnnGrid, 256, 0, stream>>>(A, i2w, i2b, I);
    conv_mfma<128, true><<<convGrid, 256, 0, stream>>>(I, wp3, A);

    conv1x1_sigmoid<<<2048, 256, 0, stream>>>(A, wo, out);
}